// Round 2
// baseline (484.884 us; speedup 1.0000x reference)
//
#include <hip/hip_runtime.h>

// FastFFN: hierarchical-gated 8-leaf GLU MLP.
//   mixture[t][l] = cn[l>>2]*cn[l>>1]*cn[l], cn[2i]=sigmoid(x.nk_i), cn[2i+1]=1-cn[2i]
//   H[t][l*512+h] = (x.w1a + b1a)*(x.w1b + b1b)*mixture   (bf16)
//   Y = H @ concat(w2) + sum_l mixture_l * b2_l           (fp32)
// R1: 2-phase double-buffered pipeline (stage-next before compute, one barrier
// per tile), XCD-chunked block swizzle, BK=64 for GEMM2.

typedef unsigned short u16;
typedef __attribute__((ext_vector_type(8))) short bf16x8;
typedef __attribute__((ext_vector_type(8))) unsigned short u16x8;
typedef __attribute__((ext_vector_type(4))) float f32x4;

__device__ __forceinline__ u16 f2bf(float f) {
  unsigned int u = __builtin_bit_cast(unsigned int, f);
  u += 0x7FFFu + ((u >> 16) & 1u);   // RNE
  return (u16)(u >> 16);
}

__device__ __forceinline__ void gload16(const void* g, void* l) {
  __builtin_amdgcn_global_load_lds(
      (const __attribute__((address_space(1))) unsigned int*)g,
      (__attribute__((address_space(3))) unsigned int*)l, 16, 0, 0);
}

// ---------------- gate: mixture (8192 x 8) ----------------
__global__ void k_gate(const float* __restrict__ x, const float* __restrict__ nk,
                       const float* __restrict__ nb, float* __restrict__ mix) {
  int token = blockIdx.x * 4 + (threadIdx.x >> 6);
  int lane = threadIdx.x & 63;
  const float* xr = x + (size_t)token * 1024;
  float a0 = 0.f, a1 = 0.f, a2 = 0.f, a3 = 0.f;
#pragma unroll
  for (int j = 0; j < 16; ++j) {
    int d = lane + j * 64;
    float xv = xr[d];
    const float* nkd = nk + d * 7;
    a0 = fmaf(xv, nkd[0], a0);
    a1 = fmaf(xv, nkd[1], a1);
    a2 = fmaf(xv, nkd[2], a2);
    a3 = fmaf(xv, nkd[3], a3);
  }
#pragma unroll
  for (int off = 32; off >= 1; off >>= 1) {
    a0 += __shfl_xor(a0, off);
    a1 += __shfl_xor(a1, off);
    a2 += __shfl_xor(a2, off);
    a3 += __shfl_xor(a3, off);
  }
  if (lane == 0) {
    float v[4] = {a0 + nb[0], a1 + nb[1], a2 + nb[2], a3 + nb[3]};
    float cn[8];
#pragma unroll
    for (int i = 0; i < 4; ++i) {
      float s = 1.f / (1.f + expf(-v[i]));
      cn[2 * i] = s;
      cn[2 * i + 1] = 1.f - s;
    }
    float* mr = mix + (size_t)token * 8;
#pragma unroll
    for (int l = 0; l < 8; ++l) mr[l] = cn[l >> 2] * cn[l >> 1] * cn[l];
  }
}

// ---------------- cast x -> bf16 ----------------
__global__ void k_cast_x(const float* __restrict__ x, u16* __restrict__ xb) {
  size_t i = (size_t)blockIdx.x * blockDim.x + threadIdx.x;  // 8 elems each
  const float4* p = (const float4*)x + i * 2;
  float4 v0 = p[0], v1 = p[1];
  u16x8 o;
  o[0] = f2bf(v0.x); o[1] = f2bf(v0.y); o[2] = f2bf(v0.z); o[3] = f2bf(v0.w);
  o[4] = f2bf(v1.x); o[5] = f2bf(v1.y); o[6] = f2bf(v1.z); o[7] = f2bf(v1.w);
  *((u16x8*)xb + i) = o;
}

// ------------- batched transpose+cast: out[(c),(r)] = in[l][r][c] -------------
__global__ void k_transpose_cast(const float* __restrict__ in, u16* __restrict__ out,
                                 int R, int C, long out_rstride, long leaf_base) {
  __shared__ float tile[32][33];
  int l = blockIdx.z;
  int c0 = blockIdx.x * 32, r0 = blockIdx.y * 32;
  const float* inl = in + (size_t)l * R * C;
  int tc = threadIdx.x & 31, tr = threadIdx.x >> 5;  // 0..7
#pragma unroll
  for (int i = 0; i < 4; ++i) {
    int r = tr + i * 8;
    tile[r][tc] = inl[(size_t)(r0 + r) * C + c0 + tc];
  }
  __syncthreads();
  u16* outl = out + (size_t)l * leaf_base;
#pragma unroll
  for (int i = 0; i < 4; ++i) {
    int c = tr + i * 8;
    outl[(size_t)(c0 + c) * out_rstride + r0 + tc] = f2bf(tile[tc][c]);
  }
}

// ---------------- GEMM1: GLU, H = (X@Wa+b1a)*(X@Wb+b1b)*mix ----------------
// X: 8192x1024 bf16 rm; Wa/Wb: 4096x1024 bf16 (NxK); H: 8192x4096 bf16
// grid: 2048 1-D (bn 32 x bm 64), XCD-chunked swizzle; BK=32 double-buffered.
__global__ __launch_bounds__(256, 2) void k_glu_gemm(
    const u16* __restrict__ Xb, const u16* __restrict__ Wa, const u16* __restrict__ Wb,
    const float* __restrict__ b1a, const float* __restrict__ b1b,
    const float* __restrict__ mix, u16* __restrict__ H) {
  constexpr int K = 1024;
  constexpr int NT = K / 32;
  __shared__ u16 lA[2][128 * 32];
  __shared__ u16 lBa[2][128 * 32];
  __shared__ u16 lBb[2][128 * 32];
  const int tid = threadIdx.x;
  const int logical = (blockIdx.x & 7) * 256 + (blockIdx.x >> 3);
  const int bn = logical & 31, bm = logical >> 5;
  const int m0 = bm * 128, n0 = bn * 128;
  const int wid = tid >> 6, lane = tid & 63;
  const int wm = (wid >> 1) * 64, wn = (wid & 1) * 64;
  const int fr = lane & 15, fk = lane >> 4;

  f32x4 accA[4][4], accB[4][4];
#pragma unroll
  for (int i = 0; i < 4; ++i)
#pragma unroll
    for (int j = 0; j < 4; ++j) {
      accA[i][j] = (f32x4)0.0f;
      accB[i][j] = (f32x4)0.0f;
    }

  const int r1 = tid >> 2, c1 = (tid & 3) * 8;

#define STAGE1(buf, k0)                                                                  \
  do {                                                                                   \
    gload16(&Xb[(size_t)(m0 + r1) * K + (k0) + c1], &lA[buf][tid * 8]);                  \
    gload16(&Xb[(size_t)(m0 + r1 + 64) * K + (k0) + c1], &lA[buf][(tid + 256) * 8]);     \
    gload16(&Wa[(size_t)(n0 + r1) * K + (k0) + c1], &lBa[buf][tid * 8]);                 \
    gload16(&Wa[(size_t)(n0 + r1 + 64) * K + (k0) + c1], &lBa[buf][(tid + 256) * 8]);    \
    gload16(&Wb[(size_t)(n0 + r1) * K + (k0) + c1], &lBb[buf][tid * 8]);                 \
    gload16(&Wb[(size_t)(n0 + r1 + 64) * K + (k0) + c1], &lBb[buf][(tid + 256) * 8]);    \
  } while (0)

  STAGE1(0, 0);
  __syncthreads();
  int cur = 0;
  for (int t = 0; t < NT; ++t) {
    if (t + 1 < NT) {
      const int nb = cur ^ 1;
      STAGE1(nb, (t + 1) * 32);
    }
    bf16x8 af[4], baf[4], bbf[4];
#pragma unroll
    for (int mf = 0; mf < 4; ++mf)
      af[mf] = *(const bf16x8*)&lA[cur][(wm + mf * 16 + fr) * 32 + fk * 8];
#pragma unroll
    for (int nf = 0; nf < 4; ++nf) {
      baf[nf] = *(const bf16x8*)&lBa[cur][(wn + nf * 16 + fr) * 32 + fk * 8];
      bbf[nf] = *(const bf16x8*)&lBb[cur][(wn + nf * 16 + fr) * 32 + fk * 8];
    }
#pragma unroll
    for (int mf = 0; mf < 4; ++mf)
#pragma unroll
      for (int nf = 0; nf < 4; ++nf) {
        accA[mf][nf] = __builtin_amdgcn_mfma_f32_16x16x32_bf16(af[mf], baf[nf], accA[mf][nf], 0, 0, 0);
        accB[mf][nf] = __builtin_amdgcn_mfma_f32_16x16x32_bf16(af[mf], bbf[nf], accB[mf][nf], 0, 0, 0);
      }
    __syncthreads();   // drains vmcnt (next tile staged) + barrier
    cur ^= 1;
  }
#undef STAGE1

  const int leaf = n0 >> 9;
  const float* b1al = b1a + (leaf << 9);
  const float* b1bl = b1b + (leaf << 9);
#pragma unroll
  for (int mf = 0; mf < 4; ++mf)
#pragma unroll
    for (int r = 0; r < 4; ++r) {
      int row = m0 + wm + mf * 16 + fk * 4 + r;
      float mv = mix[(size_t)row * 8 + leaf];
#pragma unroll
      for (int nf = 0; nf < 4; ++nf) {
        int col = n0 + wn + nf * 16 + fr;
        int hc = col & 511;
        float va = accA[mf][nf][r] + b1al[hc];
        float vb = accB[mf][nf][r] + b1bl[hc];
        H[(size_t)row * 4096 + col] = f2bf(va * vb * mv);
      }
    }
}

// ---------------- GEMM2: Y = H @ W2cat + sum_l mix_l*b2_l ----------------
// H: 8192x4096 bf16; W2T: 1024x4096 bf16 (NxK); out: 8192x1024 fp32
// grid: 512 1-D (bn 8 x bm 64), XCD-chunked swizzle; BK=64 double-buffered.
__global__ __launch_bounds__(256, 2) void k_gemm2(
    const u16* __restrict__ Hm, const u16* __restrict__ W2T,
    const float* __restrict__ b2, const float* __restrict__ mix,
    float* __restrict__ out) {
  constexpr int K = 4096;
  constexpr int BK = 64;
  constexpr int NT = K / BK;
  __shared__ u16 lA[2][128 * BK];
  __shared__ u16 lB[2][128 * BK];
  const int tid = threadIdx.x;
  const int logical = (blockIdx.x & 7) * 64 + (blockIdx.x >> 3);
  const int bn = logical & 7, bm = logical >> 3;
  const int m0 = bm * 128, n0 = bn * 128;
  const int wid = tid >> 6, lane = tid & 63;
  const int wm = (wid >> 1) * 64, wn = (wid & 1) * 64;
  const int fr = lane & 15, fk = lane >> 4;

  f32x4 acc[4][4];
#pragma unroll
  for (int i = 0; i < 4; ++i)
#pragma unroll
    for (int j = 0; j < 4; ++j) acc[i][j] = (f32x4)0.0f;

#define STAGE2(buf, k0)                                                                   \
  do {                                                                                    \
    _Pragma("unroll")                                                                     \
    for (int i = 0; i < 4; ++i) {                                                         \
      int idx = i * 256 + tid;                                                            \
      int rr = idx >> 3, cc = (idx & 7) * 8;                                              \
      gload16(&Hm[(size_t)(m0 + rr) * K + (k0) + cc], &lA[buf][idx * 8]);                 \
      gload16(&W2T[(size_t)(n0 + rr) * K + (k0) + cc], &lB[buf][idx * 8]);                \
    }                                                                                     \
  } while (0)

  STAGE2(0, 0);
  __syncthreads();
  int cur = 0;
  for (int t = 0; t < NT; ++t) {
    if (t + 1 < NT) {
      const int nb = cur ^ 1;
      STAGE2(nb, (t + 1) * BK);
    }
#pragma unroll
    for (int s = 0; s < 2; ++s) {
      bf16x8 af[4], bfr[4];
#pragma unroll
      for (int mf = 0; mf < 4; ++mf)
        af[mf] = *(const bf16x8*)&lA[cur][(wm + mf * 16 + fr) * BK + s * 32 + fk * 8];
#pragma unroll
      for (int nf = 0; nf < 4; ++nf)
        bfr[nf] = *(const bf16x8*)&lB[cur][(wn + nf * 16 + fr) * BK + s * 32 + fk * 8];
#pragma unroll
      for (int mf = 0; mf < 4; ++mf)
#pragma unroll
        for (int nf = 0; nf < 4; ++nf)
          acc[mf][nf] = __builtin_amdgcn_mfma_f32_16x16x32_bf16(af[mf], bfr[nf], acc[mf][nf], 0, 0, 0);
    }
    __syncthreads();   // drains vmcnt (next tile staged) + barrier
    cur ^= 1;
  }
#undef STAGE2

#pragma unroll
  for (int nf = 0; nf < 4; ++nf) {
    int col = n0 + wn + nf * 16 + fr;
    float bc[8];
#pragma unroll
    for (int l = 0; l < 8; ++l) bc[l] = b2[l * 1024 + col];
#pragma unroll
    for (int mf = 0; mf < 4; ++mf)
#pragma unroll
      for (int r = 0; r < 4; ++r) {
        int row = m0 + wm + mf * 16 + fk * 4 + r;
        const float* mr = mix + (size_t)row * 8;
        float bias = 0.f;
#pragma unroll
        for (int l = 0; l < 8; ++l) bias = fmaf(mr[l], bc[l], bias);
        out[(size_t)row * 1024 + col] = acc[mf][nf][r] + bias;
      }
  }
}

extern "C" void kernel_launch(void* const* d_in, const int* in_sizes, int n_in,
                              void* d_out, int out_size, void* d_ws, size_t ws_size,
                              hipStream_t stream) {
  const float* x   = (const float*)d_in[0];
  const float* nk  = (const float*)d_in[1];
  const float* nb  = (const float*)d_in[2];
  const float* w1a = (const float*)d_in[3];
  const float* w1b = (const float*)d_in[4];
  const float* b1a = (const float*)d_in[5];
  const float* b1b = (const float*)d_in[6];
  const float* w2  = (const float*)d_in[7];
  const float* b2  = (const float*)d_in[8];
  float* out = (float*)d_out;

  char* ws = (char*)d_ws;
  // layout: mixture | Xbf | W1aT | W1bT | W2T | H   (total ~109.3 MB)
  float* mix = (float*)ws;                                   // 262144 B
  u16* Xb  = (u16*)(ws + 262144);                            // 16777216 B
  u16* WaT = (u16*)(ws + 262144 + 16777216);                 // 8388608 B
  u16* WbT = (u16*)(ws + 262144 + 16777216 + 8388608);       // 8388608 B
  u16* W2T = (u16*)(ws + 262144 + 16777216 + 2 * 8388608);   // 8388608 B
  u16* Hs  = (u16*)(ws + 262144 + 16777216 + 3 * 8388608);   // 67108864 B

  k_gate<<<2048, 256, 0, stream>>>(x, nk, nb, mix);
  k_cast_x<<<4096, 256, 0, stream>>>(x, Xb);
  // w1a[l][d][h] -> WaT[(l*512+h)*1024 + d]
  k_transpose_cast<<<dim3(16, 32, 8), 256, 0, stream>>>(w1a, WaT, 1024, 512, 1024L, 512L * 1024L);
  k_transpose_cast<<<dim3(16, 32, 8), 256, 0, stream>>>(w1b, WbT, 1024, 512, 1024L, 512L * 1024L);
  // w2[l][h][dout] -> W2T[dout*4096 + l*512 + h]
  k_transpose_cast<<<dim3(32, 16, 8), 256, 0, stream>>>(w2, W2T, 512, 1024, 4096L, 512L);
  k_glu_gemm<<<2048, 256, 0, stream>>>(Xb, WaT, WbT, b1a, b1b, mix, Hs);
  k_gemm2<<<512, 256, 0, stream>>>(Hs, W2T, b2, mix, out);
}

// Round 3
// 398.102 us; speedup vs baseline: 1.2180x; 1.2180x over previous
//
#include <hip/hip_runtime.h>

// FastFFN: hierarchical-gated 8-leaf GLU MLP.
// R3: multi-phase (T3+T4) schedule with counted vmcnt, T2 LDS swizzle
// (pre-swizzled global source + swizzled ds_read), T5 setprio, T1 XCD swizzle.
// GEMM1: BM=256 BN=128 BK=64, 4 phases/K-tile, dbuf, vmcnt(2)/tile.
// GEMM2: BM=256 BN=128 BK=64, 2 phases/K-tile, A 3-buf + B 2-buf, vmcnt(4)/tile.

typedef unsigned short u16;
typedef __attribute__((ext_vector_type(8))) short bf16x8;
typedef __attribute__((ext_vector_type(8))) unsigned short u16x8;
typedef __attribute__((ext_vector_type(4))) float f32x4;

__device__ __forceinline__ u16 f2bf(float f) {
  unsigned int u = __builtin_bit_cast(unsigned int, f);
  u += 0x7FFFu + ((u >> 16) & 1u);  // RNE
  return (u16)(u >> 16);
}

__device__ __forceinline__ void gload16(const void* g, void* l) {
  __builtin_amdgcn_global_load_lds(
      (const __attribute__((address_space(1))) unsigned int*)g,
      (__attribute__((address_space(3))) unsigned int*)l, 16, 0, 0);
}

__device__ __forceinline__ f32x4 MFMA(bf16x8 a, bf16x8 b, f32x4 c) {
  return __builtin_amdgcn_mfma_f32_16x16x32_bf16(a, b, c, 0, 0, 0);
}

#define BARX()                              \
  do {                                      \
    __builtin_amdgcn_sched_barrier(0);      \
    __builtin_amdgcn_s_barrier();           \
    __builtin_amdgcn_sched_barrier(0);      \
  } while (0)

#define VMC(n)                                             \
  do {                                                     \
    asm volatile("s_waitcnt vmcnt(" #n ")" ::: "memory");  \
    __builtin_amdgcn_sched_barrier(0);                     \
  } while (0)

// ---------------- gate: mixture (8192 x 8) ----------------
__global__ void k_gate(const float* __restrict__ x, const float* __restrict__ nk,
                       const float* __restrict__ nb, float* __restrict__ mix) {
  int token = blockIdx.x * 4 + (threadIdx.x >> 6);
  int lane = threadIdx.x & 63;
  const float* xr = x + (size_t)token * 1024;
  float a0 = 0.f, a1 = 0.f, a2 = 0.f, a3 = 0.f;
#pragma unroll
  for (int j = 0; j < 16; ++j) {
    int d = lane + j * 64;
    float xv = xr[d];
    const float* nkd = nk + d * 7;
    a0 = fmaf(xv, nkd[0], a0);
    a1 = fmaf(xv, nkd[1], a1);
    a2 = fmaf(xv, nkd[2], a2);
    a3 = fmaf(xv, nkd[3], a3);
  }
#pragma unroll
  for (int off = 32; off >= 1; off >>= 1) {
    a0 += __shfl_xor(a0, off);
    a1 += __shfl_xor(a1, off);
    a2 += __shfl_xor(a2, off);
    a3 += __shfl_xor(a3, off);
  }
  if (lane == 0) {
    float v[4] = {a0 + nb[0], a1 + nb[1], a2 + nb[2], a3 + nb[3]};
    float cn[8];
#pragma unroll
    for (int i = 0; i < 4; ++i) {
      float s = 1.f / (1.f + expf(-v[i]));
      cn[2 * i] = s;
      cn[2 * i + 1] = 1.f - s;
    }
    float* mr = mix + (size_t)token * 8;
#pragma unroll
    for (int l = 0; l < 8; ++l) mr[l] = cn[l >> 2] * cn[l >> 1] * cn[l];
  }
}

// ---------------- cast x -> bf16 ----------------
__global__ void k_cast_x(const float* __restrict__ x, u16* __restrict__ xb) {
  size_t i = (size_t)blockIdx.x * blockDim.x + threadIdx.x;  // 8 elems each
  const float4* p = (const float4*)x + i * 2;
  float4 v0 = p[0], v1 = p[1];
  u16x8 o;
  o[0] = f2bf(v0.x); o[1] = f2bf(v0.y); o[2] = f2bf(v0.z); o[3] = f2bf(v0.w);
  o[4] = f2bf(v1.x); o[5] = f2bf(v1.y); o[6] = f2bf(v1.z); o[7] = f2bf(v1.w);
  *((u16x8*)xb + i) = o;
}

// ------------- batched transpose+cast: out[(c),(r)] = in[l][r][c] -------------
__global__ void k_transpose_cast(const float* __restrict__ in, u16* __restrict__ out,
                                 int R, int C, long out_rstride, long leaf_base) {
  __shared__ float tile[32][33];
  int l = blockIdx.z;
  int c0 = blockIdx.x * 32, r0 = blockIdx.y * 32;
  const float* inl = in + (size_t)l * R * C;
  int tc = threadIdx.x & 31, tr = threadIdx.x >> 5;  // 0..7
#pragma unroll
  for (int i = 0; i < 4; ++i) {
    int r = tr + i * 8;
    tile[r][tc] = inl[(size_t)(r0 + r) * C + c0 + tc];
  }
  __syncthreads();
  u16* outl = out + (size_t)l * leaf_base;
#pragma unroll
  for (int i = 0; i < 4; ++i) {
    int c = tr + i * 8;
    outl[(size_t)(c0 + c) * out_rstride + r0 + tc] = f2bf(tile[tc][c]);
  }
}

// ---------------- GEMM1: GLU, H = (X@Wa+b1a)*(X@Wb+b1b)*mix ----------------
// X: 8192x1024 bf16 rm; Wa/Wb: 4096x1024 bf16 (NxK); H: 8192x4096 bf16
// 1024 blocks (bm 32 fastest x bn 32), 512 thr, BM=256 BN=128 BK=64.
__global__ __launch_bounds__(512, 1) void k_glu_gemm(
    const u16* __restrict__ Xb, const u16* __restrict__ Wa, const u16* __restrict__ Wb,
    const float* __restrict__ b1a, const float* __restrict__ b1b,
    const float* __restrict__ mix, u16* __restrict__ H) {
  constexpr int K = 1024, NT = 16;
  __shared__ u16 sA[2][2][8192];   // [buf][half][128*64]
  __shared__ u16 sBa[2][8192];
  __shared__ u16 sBb[2][8192];
  const int tid = threadIdx.x;
  const int logical = (blockIdx.x & 7) * 128 + (blockIdx.x >> 3);
  const int bm = logical & 31, bn = logical >> 5;
  const int m0 = bm * 256, n0 = bn * 128;
  const int wid = tid >> 6, lane = tid & 63;
  const int wmh = wid >> 2;        // A half (0/1) -> rows wmh*128..+127
  const int wn = (wid & 3) * 32;   // B row base within 128
  const int fr = lane & 15, fk = lane >> 4;

  // staging chunks: c = j*512+tid; row=c>>3, swizzled 16B slot = (c&7)^(row&7)
  const int ca = tid, cb = tid + 512;
  const int ra_ = ca >> 3, sa_ = ((ca & 7) ^ (ra_ & 7)) * 8;
  const int rb_ = cb >> 3, sb_ = ((cb & 7) ^ (rb_ & 7)) * 8;

#define STG_A(v, h)                                                                     \
  do {                                                                                  \
    gload16(&Xb[(size_t)(m0 + (h)*128 + ra_) * K + (v)*64 + sa_], &sA[(v)&1][h][ca*8]); \
    gload16(&Xb[(size_t)(m0 + (h)*128 + rb_) * K + (v)*64 + sb_], &sA[(v)&1][h][cb*8]); \
  } while (0)
#define STG_BA(v)                                                                 \
  do {                                                                            \
    gload16(&Wa[(size_t)(n0 + ra_) * K + (v)*64 + sa_], &sBa[(v)&1][ca*8]);       \
    gload16(&Wa[(size_t)(n0 + rb_) * K + (v)*64 + sb_], &sBa[(v)&1][cb*8]);       \
  } while (0)
#define STG_BB(v)                                                                 \
  do {                                                                            \
    gload16(&Wb[(size_t)(n0 + ra_) * K + (v)*64 + sa_], &sBb[(v)&1][ca*8]);       \
    gload16(&Wb[(size_t)(n0 + rb_) * K + (v)*64 + sb_], &sBb[(v)&1][cb*8]);       \
  } while (0)

  f32x4 accA[8][2], accB[8][2];
#pragma unroll
  for (int i = 0; i < 8; ++i)
#pragma unroll
    for (int j = 0; j < 2; ++j) {
      accA[i][j] = (f32x4)0.0f;
      accB[i][j] = (f32x4)0.0f;
    }

  // per-lane swizzled read col offsets (elems) for K-substeps s=0,1
  const int sw0 = ((fk) ^ (fr & 7)) * 8;
  const int sw1 = ((4 + fk) ^ (fr & 7)) * 8;

  // prologue: tile0 fully + A1h0; allow A1h0 (2 loads) to fly
  STG_A(0, 0); STG_A(0, 1); STG_BA(0); STG_BB(0);
  if (NT > 1) STG_A(1, 0);
  VMC(2);
  BARX();

  bf16x8 rA[4][2], rBa[2][2], rBb[2][2];
  for (int u = 0; u < NT; ++u) {
    const u16* A_ = sA[u & 1][wmh];
    const u16* Ba_ = sBa[u & 1];
    const u16* Bb_ = sBb[u & 1];
    // ---- p1: read A(qm0)+Ba; stage A_{u+1}h1; MFMA accA qm0 ----
#pragma unroll
    for (int mfl = 0; mfl < 4; ++mfl) {
      int r = mfl * 16 + fr;
      rA[mfl][0] = *(const bf16x8*)&A_[r * 64 + sw0];
      rA[mfl][1] = *(const bf16x8*)&A_[r * 64 + sw1];
    }
#pragma unroll
    for (int nf = 0; nf < 2; ++nf) {
      int r = wn + nf * 16 + fr;
      rBa[nf][0] = *(const bf16x8*)&Ba_[r * 64 + sw0];
      rBa[nf][1] = *(const bf16x8*)&Ba_[r * 64 + sw1];
    }
    if (u + 1 < NT) STG_A(u + 1, 1);
    BARX();
    __builtin_amdgcn_s_setprio(1);
#pragma unroll
    for (int mfl = 0; mfl < 4; ++mfl)
#pragma unroll
      for (int nf = 0; nf < 2; ++nf) {
        accA[mfl][nf] = MFMA(rA[mfl][0], rBa[nf][0], accA[mfl][nf]);
        accA[mfl][nf] = MFMA(rA[mfl][1], rBa[nf][1], accA[mfl][nf]);
      }
    __builtin_amdgcn_s_setprio(0);
    BARX();
    // ---- p2: read Bb; stage Ba_{u+1}; MFMA accB qm0 ----
#pragma unroll
    for (int nf = 0; nf < 2; ++nf) {
      int r = wn + nf * 16 + fr;
      rBb[nf][0] = *(const bf16x8*)&Bb_[r * 64 + sw0];
      rBb[nf][1] = *(const bf16x8*)&Bb_[r * 64 + sw1];
    }
    if (u + 1 < NT) STG_BA(u + 1);
    BARX();
    __builtin_amdgcn_s_setprio(1);
#pragma unroll
    for (int mfl = 0; mfl < 4; ++mfl)
#pragma unroll
      for (int nf = 0; nf < 2; ++nf) {
        accB[mfl][nf] = MFMA(rA[mfl][0], rBb[nf][0], accB[mfl][nf]);
        accB[mfl][nf] = MFMA(rA[mfl][1], rBb[nf][1], accB[mfl][nf]);
      }
    __builtin_amdgcn_s_setprio(0);
    BARX();
    // ---- p3: read A(qm1); stage Bb_{u+1}; MFMA accB qm1 ----
#pragma unroll
    for (int mfl = 0; mfl < 4; ++mfl) {
      int r = 64 + mfl * 16 + fr;
      rA[mfl][0] = *(const bf16x8*)&A_[r * 64 + sw0];
      rA[mfl][1] = *(const bf16x8*)&A_[r * 64 + sw1];
    }
    if (u + 1 < NT) STG_BB(u + 1);
    BARX();
    __builtin_amdgcn_s_setprio(1);
#pragma unroll
    for (int mfl = 0; mfl < 4; ++mfl)
#pragma unroll
      for (int nf = 0; nf < 2; ++nf) {
        accB[4 + mfl][nf] = MFMA(rA[mfl][0], rBb[nf][0], accB[4 + mfl][nf]);
        accB[4 + mfl][nf] = MFMA(rA[mfl][1], rBb[nf][1], accB[4 + mfl][nf]);
      }
    __builtin_amdgcn_s_setprio(0);
    BARX();
    // ---- p4: stage A_{u+2}h0 (safe: A_u reads done at p3); MFMA accA qm1 ----
    if (u + 2 < NT) STG_A(u + 2, 0);
    BARX();
    __builtin_amdgcn_s_setprio(1);
#pragma unroll
    for (int mfl = 0; mfl < 4; ++mfl)
#pragma unroll
      for (int nf = 0; nf < 2; ++nf) {
        accA[4 + mfl][nf] = MFMA(rA[mfl][0], rBa[nf][0], accA[4 + mfl][nf]);
        accA[4 + mfl][nf] = MFMA(rA[mfl][1], rBa[nf][1], accA[4 + mfl][nf]);
      }
    __builtin_amdgcn_s_setprio(0);
    VMC(2);   // A_{u+1}h1, Ba_{u+1}, Bb_{u+1} landed; A_{u+2}h0 may fly
    BARX();
  }
#undef STG_A
#undef STG_BA
#undef STG_BB

  const int leaf = n0 >> 9;
  const float* b1al = b1a + (leaf << 9);
  const float* b1bl = b1b + (leaf << 9);
#pragma unroll
  for (int amf = 0; amf < 8; ++amf)
#pragma unroll
    for (int r = 0; r < 4; ++r) {
      int row = m0 + wmh * 128 + (amf >> 2) * 64 + (amf & 3) * 16 + fk * 4 + r;
      float mv = mix[(size_t)row * 8 + leaf];
#pragma unroll
      for (int nf = 0; nf < 2; ++nf) {
        int col = n0 + wn + nf * 16 + fr;
        int hc = col & 511;
        float va = accA[amf][nf][r] + b1al[hc];
        float vb = accB[amf][nf][r] + b1bl[hc];
        H[(size_t)row * 4096 + col] = f2bf(va * vb * mv);
      }
    }
}

// ---------------- GEMM2: Y = H @ W2cat + sum_l mix_l*b2_l ----------------
// H: 8192x4096 bf16; W2T: 1024x4096 bf16 (NxK); out: 8192x1024 fp32
// 256 blocks (bn 8 fastest x bm 32), 512 thr, BM=256 BN=128 BK=64.
// A: 3-slot rotating buffer; B: 2-slot. 2 phases/K-tile, vmcnt(4)/tile.
__global__ __launch_bounds__(512, 1) void k_gemm2(
    const u16* __restrict__ Hm, const u16* __restrict__ W2T,
    const float* __restrict__ b2, const float* __restrict__ mix,
    float* __restrict__ out) {
  constexpr int K = 4096, NT = 64;
  __shared__ u16 sA[3][2][8192];   // [slot][half][128*64]
  __shared__ u16 sB[2][8192];
  const int tid = threadIdx.x;
  const int logical = (blockIdx.x & 7) * 32 + (blockIdx.x >> 3);
  const int bn = logical & 7, bm = logical >> 3;
  const int m0 = bm * 256, n0 = bn * 128;
  const int wid = tid >> 6, lane = tid & 63;
  const int wmh = wid >> 2;
  const int wn = (wid & 3) * 32;
  const int fr = lane & 15, fk = lane >> 4;

  const int ca = tid, cb = tid + 512;
  const int ra_ = ca >> 3, sa_ = ((ca & 7) ^ (ra_ & 7)) * 8;
  const int rb_ = cb >> 3, sb_ = ((cb & 7) ^ (rb_ & 7)) * 8;

#define STG2_A(v, slot, h)                                                                 \
  do {                                                                                     \
    gload16(&Hm[(size_t)(m0 + (h)*128 + ra_) * K + (v)*64 + sa_], &sA[slot][h][ca*8]);     \
    gload16(&Hm[(size_t)(m0 + (h)*128 + rb_) * K + (v)*64 + sb_], &sA[slot][h][cb*8]);     \
  } while (0)
#define STG2_B(v)                                                                 \
  do {                                                                            \
    gload16(&W2T[(size_t)(n0 + ra_) * K + (v)*64 + sa_], &sB[(v)&1][ca*8]);       \
    gload16(&W2T[(size_t)(n0 + rb_) * K + (v)*64 + sb_], &sB[(v)&1][cb*8]);       \
  } while (0)

  f32x4 acc[8][2];
#pragma unroll
  for (int i = 0; i < 8; ++i)
#pragma unroll
    for (int j = 0; j < 2; ++j) acc[i][j] = (f32x4)0.0f;

  const int sw0 = ((fk) ^ (fr & 7)) * 8;
  const int sw1 = ((4 + fk) ^ (fr & 7)) * 8;

  // prologue: B_0, A_0 (slot0), A_1 (slot1); allow A_1 (4 loads) to fly
  STG2_B(0);
  STG2_A(0, 0, 0); STG2_A(0, 0, 1);
  STG2_A(1, 1, 0); STG2_A(1, 1, 1);
  VMC(4);
  BARX();

  int slotc = 0;  // current A slot; A_{u+2} goes to (slotc+2)%3
  bf16x8 rA[4][2], rB[2][2];
  for (int u = 0; u < NT; ++u) {
    const u16* A_ = sA[slotc][wmh];
    const u16* B_ = sB[u & 1];
    const int slot2 = slotc >= 1 ? slotc - 1 : 2;  // (slotc+2)%3
    // ---- p1: read A(qm0)+B; stage B_{u+1} then A_{u+2}h0; MFMA qm0 ----
#pragma unroll
    for (int mfl = 0; mfl < 4; ++mfl) {
      int r = mfl * 16 + fr;
      rA[mfl][0] = *(const bf16x8*)&A_[r * 64 + sw0];
      rA[mfl][1] = *(const bf16x8*)&A_[r * 64 + sw1];
    }
#pragma unroll
    for (int nf = 0; nf < 2; ++nf) {
      int r = wn + nf * 16 + fr;
      rB[nf][0] = *(const bf16x8*)&B_[r * 64 + sw0];
      rB[nf][1] = *(const bf16x8*)&B_[r * 64 + sw1];
    }
    if (u + 1 < NT) STG2_B(u + 1);
    if (u + 2 < NT) STG2_A(u + 2, slot2, 0);
    BARX();
    __builtin_amdgcn_s_setprio(1);
#pragma unroll
    for (int mfl = 0; mfl < 4; ++mfl)
#pragma unroll
      for (int nf = 0; nf < 2; ++nf) {
        acc[mfl][nf] = MFMA(rA[mfl][0], rB[nf][0], acc[mfl][nf]);
        acc[mfl][nf] = MFMA(rA[mfl][1], rB[nf][1], acc[mfl][nf]);
      }
    __builtin_amdgcn_s_setprio(0);
    BARX();
    // ---- p2: read A(qm1); stage A_{u+2}h1; MFMA qm1 ----
#pragma unroll
    for (int mfl = 0; mfl < 4; ++mfl) {
      int r = 64 + mfl * 16 + fr;
      rA[mfl][0] = *(const bf16x8*)&A_[r * 64 + sw0];
      rA[mfl][1] = *(const bf16x8*)&A_[r * 64 + sw1];
    }
    if (u + 2 < NT) STG2_A(u + 2, slot2, 1);
    BARX();
    __builtin_amdgcn_s_setprio(1);
#pragma unroll
    for (int mfl = 0; mfl < 4; ++mfl)
#pragma unroll
      for (int nf = 0; nf < 2; ++nf) {
        acc[4 + mfl][nf] = MFMA(rA[mfl][0], rB[nf][0], acc[4 + mfl][nf]);
        acc[4 + mfl][nf] = MFMA(rA[mfl][1], rB[nf][1], acc[4 + mfl][nf]);
      }
    __builtin_amdgcn_s_setprio(0);
    VMC(4);   // B_{u+1}, A_{u+1} landed; A_{u+2} (4 loads) may fly
    BARX();
    slotc = slotc < 2 ? slotc + 1 : 0;
  }
#undef STG2_A
#undef STG2_B

#pragma unroll
  for (int nf = 0; nf < 2; ++nf) {
    int col = n0 + wn + nf * 16 + fr;
    float bc[8];
#pragma unroll
    for (int l = 0; l < 8; ++l) bc[l] = b2[l * 1024 + col];
#pragma unroll
    for (int amf = 0; amf < 8; ++amf)
#pragma unroll
      for (int r = 0; r < 4; ++r) {
        int row = m0 + wmh * 128 + (amf >> 2) * 64 + (amf & 3) * 16 + fk * 4 + r;
        const float* mr = mix + (size_t)row * 8;
        float bias = 0.f;
#pragma unroll
        for (int l = 0; l < 8; ++l) bias = fmaf(mr[l], bc[l], bias);
        out[(size_t)row * 1024 + col] = acc[amf][nf][r] + bias;
      }
  }
}

extern "C" void kernel_launch(void* const* d_in, const int* in_sizes, int n_in,
                              void* d_out, int out_size, void* d_ws, size_t ws_size,
                              hipStream_t stream) {
  const float* x   = (const float*)d_in[0];
  const float* nk  = (const float*)d_in[1];
  const float* nb  = (const float*)d_in[2];
  const float* w1a = (const float*)d_in[3];
  const float* w1b = (const float*)d_in[4];
  const float* b1a = (const float*)d_in[5];
  const float* b1b = (const float*)d_in[6];
  const float* w2  = (const float*)d_in[7];
  const float* b2  = (const float*)d_in[8];
  float* out = (float*)d_out;

  char* ws = (char*)d_ws;
  // layout: mixture | Xbf | W1aT | W1bT | W2T | H   (total ~109.3 MB)
  float* mix = (float*)ws;                                   // 262144 B
  u16* Xb  = (u16*)(ws + 262144);                            // 16777216 B
  u16* WaT = (u16*)(ws + 262144 + 16777216);                 // 8388608 B
  u16* WbT = (u16*)(ws + 262144 + 16777216 + 8388608);       // 8388608 B
  u16* W2T = (u16*)(ws + 262144 + 16777216 + 2 * 8388608);   // 8388608 B
  u16* Hs  = (u16*)(ws + 262144 + 16777216 + 3 * 8388608);   // 67108864 B

  k_gate<<<2048, 256, 0, stream>>>(x, nk, nb, mix);
  k_cast_x<<<4096, 256, 0, stream>>>(x, Xb);
  // w1a[l][d][h] -> WaT[(l*512+h)*1024 + d]
  k_transpose_cast<<<dim3(16, 32, 8), 256, 0, stream>>>(w1a, WaT, 1024, 512, 1024L, 512L * 1024L);
  k_transpose_cast<<<dim3(16, 32, 8), 256, 0, stream>>>(w1b, WbT, 1024, 512, 1024L, 512L * 1024L);
  // w2[l][h][dout] -> W2T[dout*4096 + l*512 + h]
  k_transpose_cast<<<dim3(32, 16, 8), 256, 0, stream>>>(w2, W2T, 512, 1024, 4096L, 512L);
  k_glu_gemm<<<1024, 512, 0, stream>>>(Xb, WaT, WbT, b1a, b1b, mix, Hs);
  k_gemm2<<<256, 512, 0, stream>>>(Hs, W2T, b2, mix, out);
}